// Round 1
// baseline (66.545 us; speedup 1.0000x reference)
//
#include <hip/hip_runtime.h>

// db4 decomposition low-pass
static constexpr float H0 = -0.010597401784997278f;
static constexpr float H1 =  0.032883011666982945f;
static constexpr float H2 =  0.030841381835986965f;
static constexpr float H3 = -0.18703481171888114f;
static constexpr float H4 = -0.02798376941698385f;
static constexpr float H5 =  0.6308807679295904f;
static constexpr float H6 =  0.7148465705525415f;
static constexpr float H7 =  0.23037781330885523f;

// Correlation weights with the per-level 0.5 folded in (exact: *0.5 is a pow2 scale).
// w0[k] = DEC_LO[k]; w1[k] = (-1)^(7-k) * DEC_LO[7-k]
static constexpr float W0[8] = { 0.5f*H0,  0.5f*H1,  0.5f*H2,  0.5f*H3,
                                 0.5f*H4,  0.5f*H5,  0.5f*H6,  0.5f*H7 };
static constexpr float W1[8] = {-0.5f*H7,  0.5f*H6, -0.5f*H5,  0.5f*H4,
                                -0.5f*H3,  0.5f*H2, -0.5f*H1,  0.5f*H0 };

constexpr int T      = 4096;   // time length per row
constexpr int GMASK  = 1023;   // granule count per row (T/4) - 1
constexpr int BANDF  = 5120;   // padded floats per band: 1024 granules + 1 pad granule per 4

// padded float index of granule g (pad one 4-float granule every 4 granules)
static __device__ __forceinline__ int gaddr(int g) { return (g << 2) + ((g >> 2) << 2); }

// One inverse-SWT level: each thread produces 16 consecutive outputs from its
// register halo window.  window float f corresponds to position t0 - 4*D + f,
// so out[i] = sum_k W0[k]*LO[i + D*k] + W1[k]*HI[i + D*k].
template <int D, int NG>
static __device__ __forceinline__ void level(const float* __restrict__ lo_buf,
                                             const float* __restrict__ hi_buf,
                                             int g0, float res[16])
{
    float wl[NG * 4], wh[NG * 4];
#pragma unroll
    for (int j = 0; j < NG; ++j) {
        const int g = (g0 - D + j) & GMASK;          // window starts at granule g0 - D
        const int a = gaddr(g);
        const float4 vl = *(const float4*)(lo_buf + a);
        const float4 vh = *(const float4*)(hi_buf + a);
        wl[4 * j + 0] = vl.x; wl[4 * j + 1] = vl.y; wl[4 * j + 2] = vl.z; wl[4 * j + 3] = vl.w;
        wh[4 * j + 0] = vh.x; wh[4 * j + 1] = vh.y; wh[4 * j + 2] = vh.z; wh[4 * j + 3] = vh.w;
    }
#pragma unroll
    for (int i = 0; i < 16; ++i) {
        float acc = 0.0f;
#pragma unroll
        for (int k = 0; k < 8; ++k) {
            acc = fmaf(W0[k], wl[i + D * k], acc);
            acc = fmaf(W1[k], wh[i + D * k], acc);
        }
        res[i] = acc;
    }
}

static __device__ __forceinline__ void writeback(float* __restrict__ dst, int g0,
                                                 const float res[16])
{
#pragma unroll
    for (int j = 0; j < 4; ++j) {
        const int a = gaddr(g0 + j);
        *(float4*)(dst + a) = make_float4(res[4 * j + 0], res[4 * j + 1],
                                          res[4 * j + 2], res[4 * j + 3]);
    }
}

__global__ __launch_bounds__(256, 2)
void iswt_kernel(const float* __restrict__ in, float* __restrict__ out)
{
    __shared__ float lds[4][BANDF];   // 4 bands, 20 KB each = 80 KB

    const int row = blockIdx.x;
    const int tid = threadIdx.x;

    // ---- stage: deinterleave the 4 bands (coalesced float4 loads) ----
    const float4* __restrict__ src = (const float4*)(in + (size_t)row * (T * 4));
#pragma unroll
    for (int j = 0; j < 16; ++j) {
        const int p = tid + 256 * j;          // position in row
        const float4 v = src[p];              // (band0, band1, band2, band3) at p
        const int a = p + ((p >> 4) << 2);    // padded scalar float index
        lds[0][a] = v.x;   // cA_3
        lds[1][a] = v.y;   // cD_3
        lds[2][a] = v.z;   // cD_2
        lds[3][a] = v.w;   // cD_1
    }
    __syncthreads();

    const int g0 = tid << 2;   // base granule of this thread's 16-output chunk
    float res[16];

    // Level 1: lo = band3 (cD_1), hi = band2 (cD_2), dilation 4
    level<4, 11>(&lds[3][0], &lds[2][0], g0, res);
    __syncthreads();
    writeback(&lds[3][0], g0, res);           // band3/band2 dead -> reuse buf3
    __syncthreads();

    // Level 2: lo = res (buf3), hi = band1 (cD_3), dilation 2
    level<2, 8>(&lds[3][0], &lds[1][0], g0, res);
    __syncthreads();
    writeback(&lds[1][0], g0, res);           // reuse buf1
    __syncthreads();

    // Level 3: lo = res (buf1), hi = band0 (cA_3), dilation 1 -> global
    level<1, 6>(&lds[1][0], &lds[0][0], g0, res);

    float* __restrict__ o = out + (size_t)row * T + (tid << 4);
#pragma unroll
    for (int j = 0; j < 4; ++j)
        *(float4*)(o + 4 * j) = make_float4(res[4 * j + 0], res[4 * j + 1],
                                            res[4 * j + 2], res[4 * j + 3]);
}

extern "C" void kernel_launch(void* const* d_in, const int* in_sizes, int n_in,
                              void* d_out, int out_size, void* d_ws, size_t ws_size,
                              hipStream_t stream)
{
    const float* coeffs = (const float*)d_in[0];
    float* out = (float*)d_out;
    const int nrows = in_sizes[0] / (T * 4);   // B*N = 4096
    iswt_kernel<<<nrows, 256, 0, stream>>>(coeffs, out);
}